// Round 1
// baseline (2226.913 us; speedup 1.0000x reference)
//
#include <hip/hip_runtime.h>

constexpr int D = 128;

// ---------------------------------------------------------------- CSR build
__global__ void count_edges(const int* __restrict__ dst, int E, int* __restrict__ cnt) {
    int i = blockIdx.x * blockDim.x + threadIdx.x;
    int stride = gridDim.x * blockDim.x;
    for (; i < E; i += stride) atomicAdd(&cnt[dst[i]], 1);
}

__global__ void place_edges(const int* __restrict__ src, const int* __restrict__ dst, int E,
                            int* __restrict__ cur, int* __restrict__ csr) {
    int i = blockIdx.x * blockDim.x + threadIdx.x;
    int stride = gridDim.x * blockDim.x;
    for (; i < E; i += stride) {
        int p = atomicAdd(&cur[dst[i]], 1);
        csr[p] = src[i];
    }
}

// One block per array: exclusive scan + cursor copy + inv-count.
__global__ __launch_bounds__(1024) void scan3(
    const int* __restrict__ c0, int n0, int* o0, int* u0, float* v0,
    const int* __restrict__ c1, int n1, int* o1, int* u1, float* v1,
    const int* __restrict__ c2, int n2, int* o2, int* u2, float* v2) {
    const int* cnt; int n; int* offs; int* cur; float* inv;
    if (blockIdx.x == 0)      { cnt = c0; n = n0; offs = o0; cur = u0; inv = v0; }
    else if (blockIdx.x == 1) { cnt = c1; n = n1; offs = o1; cur = u1; inv = v1; }
    else                      { cnt = c2; n = n2; offs = o2; cur = u2; inv = v2; }

    __shared__ int s[1024];
    __shared__ int carry;
    int tid = threadIdx.x;
    if (tid == 0) carry = 0;
    __syncthreads();
    for (int base = 0; base < n; base += 1024) {
        int i = base + tid;
        int v = (i < n) ? cnt[i] : 0;
        s[tid] = v;
        __syncthreads();
        #pragma unroll
        for (int off = 1; off < 1024; off <<= 1) {
            int t = (tid >= off) ? s[tid - off] : 0;
            __syncthreads();
            s[tid] += t;
            __syncthreads();
        }
        int c = carry;
        if (i < n) {
            int excl = c + s[tid] - v;
            offs[i] = excl;
            cur[i]  = excl;
            inv[i]  = 1.0f / fmaxf((float)v, 1.0f);
        }
        __syncthreads();
        if (tid == 1023) carry = c + s[1023];
        __syncthreads();
    }
    if (tid == 0) offs[n] = carry;
}

// ------------------------------------------------- combined Wr / bias (cui)
__global__ void combine_wb(const float* __restrict__ Wr, const float* __restrict__ b,
                           float* __restrict__ Wcomb, float* __restrict__ bcomb) {
    int i = blockIdx.x * blockDim.x + threadIdx.x;
    int stride = gridDim.x * blockDim.x;
    for (int idx = i; idx < 4 * D * D; idx += stride) {
        int fl = idx >> 14, r = idx & 16383;
        int base = fl * 3 * D * D;
        Wcomb[idx] = Wr[base + r] + Wr[base + D * D + r];
    }
    for (int idx = i; idx < 4 * D; idx += stride) {
        int fl = idx >> 7, r = idx & 127;
        int base = fl * 3 * D;
        bcomb[idx] = b[base + r] + b[base + D + r];
    }
}

// ----------------------------------------------------- CSR mean aggregation
// One wave per destination row; lane handles 2 columns (float2 = 512B/row).
__global__ void agg_mean(const float* __restrict__ x, const int* __restrict__ csr,
                         const int* __restrict__ offs, const float* __restrict__ inv,
                         int n_dst, float* __restrict__ out) {
    int wave = (int)((blockIdx.x * (size_t)blockDim.x + threadIdx.x) >> 6);
    int lane = threadIdx.x & 63;
    if (wave >= n_dst) return;
    int start = offs[wave], end = offs[wave + 1];
    float2 a0 = {0, 0}, a1 = {0, 0}, a2 = {0, 0}, a3 = {0, 0};
    int e = start;
    for (; e + 4 <= end; e += 4) {
        int s0 = csr[e], s1 = csr[e + 1], s2 = csr[e + 2], s3 = csr[e + 3];
        float2 q0 = ((const float2*)(x + (size_t)s0 * D))[lane];
        float2 q1 = ((const float2*)(x + (size_t)s1 * D))[lane];
        float2 q2 = ((const float2*)(x + (size_t)s2 * D))[lane];
        float2 q3 = ((const float2*)(x + (size_t)s3 * D))[lane];
        a0.x += q0.x; a0.y += q0.y;
        a1.x += q1.x; a1.y += q1.y;
        a2.x += q2.x; a2.y += q2.y;
        a3.x += q3.x; a3.y += q3.y;
    }
    for (; e < end; ++e) {
        int s0 = csr[e];
        float2 q0 = ((const float2*)(x + (size_t)s0 * D))[lane];
        a0.x += q0.x; a0.y += q0.y;
    }
    float sc = inv[wave];
    float2 r;
    r.x = ((a0.x + a1.x) + (a2.x + a3.x)) * sc;
    r.y = ((a0.y + a1.y) + (a2.y + a3.y)) * sc;
    ((float2*)(out + (size_t)wave * D))[lane] = r;
}

// --------------------------------------------------------------- fused GEMM
// out[n,o] = sum_p sum_k A_p[n,k] * W_p[o,k] + bias[o]   (W row-major [out,in])
// mode: 0 = relu-store, 1 = store, 2 = max-with-existing
__global__ __launch_bounds__(256) void gemm_fused(
    const float* __restrict__ A0, const float* __restrict__ W0,
    const float* __restrict__ A1, const float* __restrict__ W1,
    const float* __restrict__ A2, const float* __restrict__ W2,
    const float* __restrict__ bias, float* __restrict__ out,
    int N, int nPairs, int mode) {
    __shared__ float As[32][68];    // [kk][row], padded stride
    __shared__ float Ws[32][132];   // [kk][col], padded stride

    int tid  = threadIdx.x;
    int colg = tid & 31;      // 32 col groups * 4 cols
    int rowg = tid >> 5;      // 8 row groups * 8 rows
    int blockRow = blockIdx.x * 64;

    float acc[8][4];
    #pragma unroll
    for (int i = 0; i < 8; ++i)
        #pragma unroll
        for (int j = 0; j < 4; ++j) acc[i][j] = 0.f;

    const float* Aarr[3] = {A0, A1, A2};
    const float* Warr[3] = {W0, W1, W2};

    int r  = tid >> 3;           // 0..31
    int kp = (tid & 7) << 2;     // 0,4,...,28

    for (int p = 0; p < nPairs; ++p) {
        const float* A = Aarr[p];
        const float* W = Warr[p];
        for (int k0 = 0; k0 < D; k0 += 32) {
            // A tile: 64 rows x 32 k
            #pragma unroll
            for (int rr = 0; rr < 2; ++rr) {
                int row  = r + rr * 32;
                int grow = blockRow + row;
                float4 v = make_float4(0.f, 0.f, 0.f, 0.f);
                if (grow < N) v = *(const float4*)(A + (size_t)grow * D + k0 + kp);
                As[kp + 0][row] = v.x; As[kp + 1][row] = v.y;
                As[kp + 2][row] = v.z; As[kp + 3][row] = v.w;
            }
            // W tile: 128 out x 32 k
            #pragma unroll
            for (int oo = 0; oo < 4; ++oo) {
                int oc = r + oo * 32;
                float4 w = *(const float4*)(W + (size_t)oc * D + k0 + kp);
                Ws[kp + 0][oc] = w.x; Ws[kp + 1][oc] = w.y;
                Ws[kp + 2][oc] = w.z; Ws[kp + 3][oc] = w.w;
            }
            __syncthreads();
            #pragma unroll
            for (int kk = 0; kk < 32; ++kk) {
                float4 aLo = *(const float4*)&As[kk][rowg * 8];
                float4 aHi = *(const float4*)&As[kk][rowg * 8 + 4];
                float4 wv  = *(const float4*)&Ws[kk][colg * 4];
                float a[8] = {aLo.x, aLo.y, aLo.z, aLo.w, aHi.x, aHi.y, aHi.z, aHi.w};
                float w[4] = {wv.x, wv.y, wv.z, wv.w};
                #pragma unroll
                for (int i = 0; i < 8; ++i)
                    #pragma unroll
                    for (int j = 0; j < 4; ++j) acc[i][j] += a[i] * w[j];
            }
            __syncthreads();
        }
    }

    float4 bv = *(const float4*)(bias + colg * 4);
    float bb[4] = {bv.x, bv.y, bv.z, bv.w};
    #pragma unroll
    for (int i = 0; i < 8; ++i) {
        int grow = blockRow + rowg * 8 + i;
        if (grow >= N) continue;
        float4 v;
        v.x = acc[i][0] + bb[0];
        v.y = acc[i][1] + bb[1];
        v.z = acc[i][2] + bb[2];
        v.w = acc[i][3] + bb[3];
        if (mode == 0) {
            v.x = fmaxf(v.x, 0.f); v.y = fmaxf(v.y, 0.f);
            v.z = fmaxf(v.z, 0.f); v.w = fmaxf(v.w, 0.f);
        }
        float* po = out + (size_t)grow * D + colg * 4;
        if (mode == 2) {
            float4 old = *(const float4*)po;
            v.x = fmaxf(v.x, old.x); v.y = fmaxf(v.y, old.y);
            v.z = fmaxf(v.z, old.z); v.w = fmaxf(v.w, old.w);
        }
        *(float4*)po = v;
    }
}

// ------------------------------------------------------------------- driver
extern "C" void kernel_launch(void* const* d_in, const int* in_sizes, int n_in,
                              void* d_out, int out_size, void* d_ws, size_t ws_size,
                              hipStream_t stream) {
    const float* x_cui  = (const float*)d_in[0];
    const float* x_code = (const float*)d_in[1];
    const int*   ei_cc  = (const int*)d_in[2];
    const int*   ei_kc  = (const int*)d_in[3];
    const int*   ei_ck  = (const int*)d_in[4];
    const float* Wl     = (const float*)d_in[5];
    const float* Wr     = (const float*)d_in[6];
    const float* b      = (const float*)d_in[7];

    const int N_CUI  = in_sizes[0] / D;
    const int N_CODE = in_sizes[1] / D;
    const int E_CC   = in_sizes[2] / 2;
    const int E_KC   = in_sizes[3] / 2;
    const int E_CK   = in_sizes[4] / 2;

    char* ws = (char*)d_ws;
    size_t off = 0;
    auto alloc = [&](size_t bytes) -> char* {
        char* p = ws + off;
        off += (bytes + 255) & ~(size_t)255;
        return p;
    };

    // counts (contiguous for one memset)
    int* cnt_cc = (int*)alloc((size_t)N_CUI * 4);
    int* cnt_kc = (int*)alloc((size_t)N_CUI * 4);
    int* cnt_ck = (int*)alloc((size_t)N_CODE * 4);
    size_t cntBytes = off;

    int* offs_cc = (int*)alloc(((size_t)N_CUI + 1) * 4);
    int* offs_kc = (int*)alloc(((size_t)N_CUI + 1) * 4);
    int* offs_ck = (int*)alloc(((size_t)N_CODE + 1) * 4);
    int* cur_cc  = (int*)alloc(((size_t)N_CUI + 1) * 4);
    int* cur_kc  = (int*)alloc(((size_t)N_CUI + 1) * 4);
    int* cur_ck  = (int*)alloc(((size_t)N_CODE + 1) * 4);
    float* inv_cc = (float*)alloc((size_t)N_CUI * 4);
    float* inv_kc = (float*)alloc((size_t)N_CUI * 4);
    float* inv_ck = (float*)alloc((size_t)N_CODE * 4);
    int* csr_cc = (int*)alloc((size_t)E_CC * 4);
    int* csr_kc = (int*)alloc((size_t)E_KC * 4);
    int* csr_ck = (int*)alloc((size_t)E_CK * 4);

    float* Wcomb = (float*)alloc((size_t)4 * D * D * 4);
    float* bcomb = (float*)alloc((size_t)4 * D * 4);

    float* agg_cc = (float*)alloc((size_t)N_CUI * D * 4);
    float* agg_kc = (float*)alloc((size_t)N_CUI * D * 4);
    float* agg_ck = (float*)alloc((size_t)N_CODE * D * 4);
    float* h_cui0 = (float*)alloc((size_t)N_CUI * D * 4);
    float* h_cui1 = (float*)alloc((size_t)N_CUI * D * 4);
    float* h_code0 = (float*)alloc((size_t)N_CODE * D * 4);
    float* h_code1 = (float*)alloc((size_t)N_CODE * D * 4);

    float* out_cui  = (float*)d_out;
    float* out_code = (float*)d_out + (size_t)N_CUI * D;

    auto WlP = [&](int f, int l, int t) { return Wl + (size_t)((f * 2 + l) * 3 + t) * D * D; };
    auto WrP = [&](int f, int l, int t) { return Wr + (size_t)((f * 2 + l) * 3 + t) * D * D; };
    auto bP  = [&](int f, int l, int t) { return b + (size_t)((f * 2 + l) * 3 + t) * D; };

    // ---- CSR build (edge structure constant across layers/filters) ----
    hipMemsetAsync(d_ws, 0, cntBytes, stream);
    count_edges<<<2048, 256, 0, stream>>>(ei_cc + E_CC, E_CC, cnt_cc);
    count_edges<<<2048, 256, 0, stream>>>(ei_kc + E_KC, E_KC, cnt_kc);
    count_edges<<<2048, 256, 0, stream>>>(ei_ck + E_CK, E_CK, cnt_ck);
    scan3<<<3, 1024, 0, stream>>>(cnt_cc, N_CUI, offs_cc, cur_cc, inv_cc,
                                  cnt_kc, N_CUI, offs_kc, cur_kc, inv_kc,
                                  cnt_ck, N_CODE, offs_ck, cur_ck, inv_ck);
    place_edges<<<2048, 256, 0, stream>>>(ei_cc, ei_cc + E_CC, E_CC, cur_cc, csr_cc);
    place_edges<<<2048, 256, 0, stream>>>(ei_kc, ei_kc + E_KC, E_KC, cur_kc, csr_kc);
    place_edges<<<2048, 256, 0, stream>>>(ei_ck, ei_ck + E_CK, E_CK, cur_ck, csr_ck);
    combine_wb<<<256, 256, 0, stream>>>(Wr, b, Wcomb, bcomb);

    dim3 aggBlk(256);
    dim3 aggGridCui((N_CUI + 3) / 4), aggGridCode((N_CODE + 3) / 4);
    int gCui = (N_CUI + 63) / 64, gCode = (N_CODE + 63) / 64;

    // ---- layer 0: aggregations shared across filters ----
    agg_mean<<<aggGridCui, aggBlk, 0, stream>>>(x_cui, csr_cc, offs_cc, inv_cc, N_CUI, agg_cc);
    agg_mean<<<aggGridCui, aggBlk, 0, stream>>>(x_code, csr_kc, offs_kc, inv_kc, N_CUI, agg_kc);
    agg_mean<<<aggGridCode, aggBlk, 0, stream>>>(x_cui, csr_ck, offs_ck, inv_ck, N_CODE, agg_ck);

    // layer 0 transforms (relu)
    float* hc[2] = {h_cui0, h_cui1};
    float* hk[2] = {h_code0, h_code1};
    for (int f = 0; f < 2; ++f) {
        gemm_fused<<<gCui, 256, 0, stream>>>(
            agg_cc, WlP(f, 0, 0), agg_kc, WlP(f, 0, 1), x_cui, Wcomb + (size_t)(f * 2 + 0) * D * D,
            bcomb + (size_t)(f * 2 + 0) * D, hc[f], N_CUI, 3, 0);
        gemm_fused<<<gCode, 256, 0, stream>>>(
            agg_ck, WlP(f, 0, 2), x_code, WrP(f, 0, 2), nullptr, nullptr,
            bP(f, 0, 2), hk[f], N_CODE, 2, 0);
    }

    // ---- layer 1: per-filter aggregation + final transform (store / max) ----
    for (int f = 0; f < 2; ++f) {
        agg_mean<<<aggGridCui, aggBlk, 0, stream>>>(hc[f], csr_cc, offs_cc, inv_cc, N_CUI, agg_cc);
        agg_mean<<<aggGridCui, aggBlk, 0, stream>>>(hk[f], csr_kc, offs_kc, inv_kc, N_CUI, agg_kc);
        agg_mean<<<aggGridCode, aggBlk, 0, stream>>>(hc[f], csr_ck, offs_ck, inv_ck, N_CODE, agg_ck);
        int mode = (f == 0) ? 1 : 2;
        gemm_fused<<<gCui, 256, 0, stream>>>(
            agg_cc, WlP(f, 1, 0), agg_kc, WlP(f, 1, 1), hc[f], Wcomb + (size_t)(f * 2 + 1) * D * D,
            bcomb + (size_t)(f * 2 + 1) * D, out_cui, N_CUI, 3, mode);
        gemm_fused<<<gCode, 256, 0, stream>>>(
            agg_ck, WlP(f, 1, 2), hk[f], WrP(f, 1, 2), nullptr, nullptr,
            bP(f, 1, 2), out_code, N_CODE, 2, mode);
    }
}

// Round 3
// 1851.531 us; speedup vs baseline: 1.2027x; 1.2027x over previous
//
#include <hip/hip_runtime.h>

typedef unsigned short ushortT;
typedef __attribute__((ext_vector_type(8))) short short8v;
typedef __attribute__((ext_vector_type(4))) float float4v;

constexpr int D = 128;

// ---------------------------------------------------------- split helpers
// f32 v == hi + lo to ~2^-16 relative; stored as bf16 bit patterns.
__device__ __forceinline__ void splitf(float v, short& h, short& l) {
    unsigned u = __float_as_uint(v);
    unsigned hb = u & 0xffff0000u;
    float r = v - __uint_as_float(hb);   // exact (same exponent)
    h = (short)(u >> 16);
    l = (short)(__float_as_uint(r) >> 16);
}
__device__ __forceinline__ unsigned packsplit(float v) {
    unsigned u = __float_as_uint(v);
    unsigned hb = u & 0xffff0000u;
    float r = v - __uint_as_float(hb);
    return hb | (__float_as_uint(r) >> 16);
}
__device__ __forceinline__ float unpackf(unsigned p) {
    return __uint_as_float(p & 0xffff0000u) + __uint_as_float(p << 16);
}

// ---------------------------------------------------------------- CSR build
__global__ void count_all(const int* __restrict__ ecc, const int* __restrict__ ekc,
                          const int* __restrict__ eck, int Ecc, int Ekc, int Eck,
                          int ncui, int* __restrict__ cnt) {
    int ET = Ecc + Ekc + Eck;
    for (int e = blockIdx.x * blockDim.x + threadIdx.x; e < ET;
         e += gridDim.x * blockDim.x) {
        int d;
        if (e < Ecc)            d = ecc[Ecc + e];
        else if (e < Ecc + Ekc) d = ncui + ekc[Ekc + (e - Ecc)];
        else                    d = 2 * ncui + eck[Eck + (e - Ecc - Ekc)];
        atomicAdd(&cnt[d], 1);
    }
}

__global__ void place_all(const int* __restrict__ ecc, const int* __restrict__ ekc,
                          const int* __restrict__ eck, int Ecc, int Ekc, int Eck,
                          int ncui, int* __restrict__ cur, int* __restrict__ csr) {
    int ET = Ecc + Ekc + Eck;
    for (int e = blockIdx.x * blockDim.x + threadIdx.x; e < ET;
         e += gridDim.x * blockDim.x) {
        int d, s;
        if (e < Ecc)            { s = ecc[e]; d = ecc[Ecc + e]; }
        else if (e < Ecc + Ekc) { int le = e - Ecc; s = ekc[le]; d = ncui + ekc[Ekc + le]; }
        else                    { int le = e - Ecc - Ekc; s = eck[le]; d = 2 * ncui + eck[Eck + le]; }
        int p = atomicAdd(&cur[d], 1);
        csr[p] = s;
    }
}

// 3-phase multi-block exclusive scan over the concatenated count array.
__global__ __launch_bounds__(1024) void scan_s1(const int* __restrict__ cnt, int n4,
                                                int* __restrict__ blockSums) {
    __shared__ int red[1024];
    int t = threadIdx.x;
    int i = blockIdx.x * 1024 + t;
    int4 v = (i < n4) ? ((const int4*)cnt)[i] : make_int4(0, 0, 0, 0);
    red[t] = v.x + v.y + v.z + v.w;
    __syncthreads();
    for (int s = 512; s > 0; s >>= 1) {
        if (t < s) red[t] += red[t + s];
        __syncthreads();
    }
    if (t == 0) blockSums[blockIdx.x] = red[0];
}

__global__ __launch_bounds__(1024) void scan_s2(int* __restrict__ bs, int nb,
                                                int* __restrict__ offs, int NT) {
    __shared__ int s[1024];
    int t = threadIdx.x;
    int v = (t < nb) ? bs[t] : 0;
    s[t] = v;
    __syncthreads();
    for (int d = 1; d < 1024; d <<= 1) {
        int u = (t >= d) ? s[t - d] : 0;
        __syncthreads();
        s[t] += u;
        __syncthreads();
    }
    if (t < nb) bs[t] = s[t] - v;        // exclusive base per block
    if (t == 0) offs[NT] = s[1023];      // grand total sentinel
}

__global__ __launch_bounds__(1024) void scan_s3(const int* __restrict__ cnt, int n,
                                                const int* __restrict__ blockSums,
                                                int* __restrict__ offs, int* __restrict__ cur,
                                                float* __restrict__ inv) {
    __shared__ int sc[1024];
    int t = threadIdx.x;
    int n4 = n >> 2;
    int i4 = blockIdx.x * 1024 + t;
    int4 v = (i4 < n4) ? ((const int4*)cnt)[i4] : make_int4(0, 0, 0, 0);
    int s1 = v.x, s2 = s1 + v.y, s3 = s2 + v.z, s4 = s3 + v.w;
    sc[t] = s4;
    __syncthreads();
    for (int d = 1; d < 1024; d <<= 1) {
        int u = (t >= d) ? sc[t - d] : 0;
        __syncthreads();
        sc[t] += u;
        __syncthreads();
    }
    int base = sc[t] - s4 + blockSums[blockIdx.x];
    if (i4 < n4) {
        int4 o;
        o.x = base; o.y = base + s1; o.z = base + s2; o.w = base + s3;
        ((int4*)offs)[i4] = o;
        ((int4*)cur)[i4]  = o;
        float4 iv;
        iv.x = 1.f / fmaxf((float)v.x, 1.f);
        iv.y = 1.f / fmaxf((float)v.y, 1.f);
        iv.z = 1.f / fmaxf((float)v.z, 1.f);
        iv.w = 1.f / fmaxf((float)v.w, 1.f);
        ((float4*)inv)[i4] = iv;
    }
}

// --------------------------------- weight reorder to MFMA-frag-major hi/lo
// 20 pair-matrices, each 128x128: [half][nt(8)][ks(4)][lane(64)][8 bf16].
// mat id m = fl*5 + j;  j: 0=Wl(t0) 1=Wl(t1) 2=Wr(t0)+Wr(t1) 3=Wl(t2) 4=Wr(t2)
__global__ void prep_w(const float* __restrict__ Wl, const float* __restrict__ Wr,
                       const float* __restrict__ b, ushortT* __restrict__ Wp,
                       float* __restrict__ bcomb) {
    if (blockIdx.x == 160) {   // combined cui bias: b(t0)+b(t1) per (f,l)
        for (int t = threadIdx.x; t < 512; t += 256) {
            int fl = t >> 7, c = t & 127;
            bcomb[t] = b[(fl * 3 + 0) * D + c] + b[(fl * 3 + 1) * D + c];
        }
        return;
    }
    int id = blockIdx.x * 256 + threadIdx.x;   // 0..40959
    int mat = id >> 11;
    int slot = id & 2047;
    int nt = slot >> 8, rem = slot & 255, ks = rem >> 6, lane = rem & 63;
    int row = nt * 16 + (lane & 15);
    int k0 = ks * 32 + ((lane >> 4) << 3);
    int fl = mat / 5, j = mat % 5;
    const float* s1;
    const float* s2 = nullptr;
    if (j < 2)       s1 = Wl + (size_t)(fl * 3 + j) * D * D;
    else if (j == 2) { s1 = Wr + (size_t)(fl * 3 + 0) * D * D;
                       s2 = Wr + (size_t)(fl * 3 + 1) * D * D; }
    else if (j == 3) s1 = Wl + (size_t)(fl * 3 + 2) * D * D;
    else             s1 = Wr + (size_t)(fl * 3 + 2) * D * D;

    unsigned hw[4], lw[4];
    #pragma unroll
    for (int q = 0; q < 4; ++q) {
        short h0, l0, h1, l1;
        float v0 = s1[row * D + k0 + 2 * q];
        float v1 = s1[row * D + k0 + 2 * q + 1];
        if (s2) { v0 += s2[row * D + k0 + 2 * q]; v1 += s2[row * D + k0 + 2 * q + 1]; }
        splitf(v0, h0, l0);
        splitf(v1, h1, l1);
        hw[q] = (unsigned short)h0 | ((unsigned)(unsigned short)h1 << 16);
        lw[q] = (unsigned short)l0 | ((unsigned)(unsigned short)l1 << 16);
    }
    ushortT* dh = Wp + (size_t)mat * 32768 + slot * 8;
    *(uint4*)dh           = make_uint4(hw[0], hw[1], hw[2], hw[3]);
    *(uint4*)(dh + 16384) = make_uint4(lw[0], lw[1], lw[2], lw[3]);
}

// ----------------------------------------------------- CSR mean aggregation
// One wave per global dst row; lane handles 2 cols. Output = packed hi|lo u32.
__global__ void agg_all(const float* __restrict__ src_cui_f, const float* __restrict__ src_code_f,
                        const unsigned* __restrict__ src_cui_p, const unsigned* __restrict__ src_code_p,
                        int packed, const int* __restrict__ csr, const int* __restrict__ offs,
                        const float* __restrict__ inv, int ncui, int ncode,
                        unsigned* __restrict__ outP) {
    int NT = 2 * ncui + ncode;
    int gw = (int)((blockIdx.x * (size_t)blockDim.x + threadIdx.x) >> 6);
    int lane = threadIdx.x & 63;
    if (gw >= NT) return;
    bool isCode = (gw >= ncui) && (gw < 2 * ncui);   // kc region gathers code feats
    int st = offs[gw], en = offs[gw + 1];
    float a0 = 0, a1 = 0, b0 = 0, b1 = 0, c0 = 0, c1 = 0, d0 = 0, d1 = 0;
    int e = st;
    if (!packed) {
        const float* s = isCode ? src_code_f : src_cui_f;
        for (; e + 4 <= en; e += 4) {
            int i0 = csr[e], i1 = csr[e + 1], i2 = csr[e + 2], i3 = csr[e + 3];
            float2 q0 = ((const float2*)(s + (size_t)i0 * D))[lane];
            float2 q1 = ((const float2*)(s + (size_t)i1 * D))[lane];
            float2 q2 = ((const float2*)(s + (size_t)i2 * D))[lane];
            float2 q3 = ((const float2*)(s + (size_t)i3 * D))[lane];
            a0 += q0.x; a1 += q0.y; b0 += q1.x; b1 += q1.y;
            c0 += q2.x; c1 += q2.y; d0 += q3.x; d1 += q3.y;
        }
        for (; e < en; ++e) {
            float2 q = ((const float2*)(s + (size_t)csr[e] * D))[lane];
            a0 += q.x; a1 += q.y;
        }
    } else {
        const unsigned* s = isCode ? src_code_p : src_cui_p;
        for (; e + 4 <= en; e += 4) {
            int i0 = csr[e], i1 = csr[e + 1], i2 = csr[e + 2], i3 = csr[e + 3];
            uint2 q0 = ((const uint2*)(s + (size_t)i0 * D))[lane];
            uint2 q1 = ((const uint2*)(s + (size_t)i1 * D))[lane];
            uint2 q2 = ((const uint2*)(s + (size_t)i2 * D))[lane];
            uint2 q3 = ((const uint2*)(s + (size_t)i3 * D))[lane];
            a0 += unpackf(q0.x); a1 += unpackf(q0.y);
            b0 += unpackf(q1.x); b1 += unpackf(q1.y);
            c0 += unpackf(q2.x); c1 += unpackf(q2.y);
            d0 += unpackf(q3.x); d1 += unpackf(q3.y);
        }
        for (; e < en; ++e) {
            uint2 q = ((const uint2*)(s + (size_t)csr[e] * D))[lane];
            a0 += unpackf(q.x); a1 += unpackf(q.y);
        }
    }
    float sc = inv[gw];
    float r0 = ((a0 + b0) + (c0 + d0)) * sc;
    float r1 = ((a1 + b1) + (c1 + d1)) * sc;
    ((uint2*)(outP + (size_t)gw * D))[lane] = make_uint2(packsplit(r0), packsplit(r1));
}

// -------------------------------------------------- split-bf16 MFMA GEMM
// out[m,n] = sum_p sum_k A_p[m,k] * W_p[n,k] + bias[n]
// A packed u32 (hi|lo); last pair may instead be raw f32 (Alast_f32 != null).
// W in frag-major hi/lo planes (32768 ushorts per pair-matrix).
// mode: 0 = relu -> packed store to outP; 1 = f32 store; 2 = f32 max-store.
__global__ __launch_bounds__(256, 2) void gemm_split(
    const unsigned* __restrict__ A0, const unsigned* __restrict__ A1,
    const unsigned* __restrict__ A2, const float* __restrict__ Alast_f32,
    const ushortT* __restrict__ W0, const ushortT* __restrict__ W1,
    const ushortT* __restrict__ W2, const float* __restrict__ bias,
    float* __restrict__ outF, unsigned* __restrict__ outP,
    int M, int nPairs, int mode) {
    __shared__ ushortT wlds[32768];   // 64 KiB: [half][nt][ks][lane][8]

    int tid = threadIdx.x;
    int lane = tid & 63;
    int w = tid >> 6;
    int rowTile = blockIdx.x * 256 + w * 64;   // this wave's 64 rows
    int rl = lane & 15;
    int kg = (lane >> 4) << 3;                 // k sub-offset 0/8/16/24

    float4v acc[4][8];
    #pragma unroll
    for (int mt = 0; mt < 4; ++mt)
        #pragma unroll
        for (int nt = 0; nt < 8; ++nt)
            acc[mt][nt] = (float4v){0.f, 0.f, 0.f, 0.f};

    const unsigned* Aarr[3] = {A0, A1, A2};
    const ushortT* Warr[3] = {W0, W1, W2};

    for (int p = 0; p < nPairs; ++p) {
        __syncthreads();
        {
            const ushortT* Wsrc = Warr[p];
            #pragma unroll
            for (int i = 0; i < 16; ++i)
                *(int4*)&wlds[i * 2048 + tid * 8] = *(const int4*)&Wsrc[i * 2048 + tid * 8];
        }
        __syncthreads();
        bool f32A = (Alast_f32 != nullptr) && (p == nPairs - 1);
        const unsigned* A = Aarr[p];
        #pragma unroll
        for (int ks = 0; ks < 4; ++ks) {
            short8v ah[4], al[4];
            #pragma unroll
            for (int mt = 0; mt < 4; ++mt) {
                int row = rowTile + mt * 16 + rl;
                if (row < M) {
                    size_t boff = (size_t)row * D + ks * 32 + kg;
                    if (!f32A) {
                        uint4 q0 = *(const uint4*)(A + boff);
                        uint4 q1 = *(const uint4*)(A + boff + 4);
                        unsigned qa[8] = {q0.x, q0.y, q0.z, q0.w, q1.x, q1.y, q1.z, q1.w};
                        #pragma unroll
                        for (int jj = 0; jj < 8; ++jj) {
                            ah[mt][jj] = (short)(qa[jj] >> 16);
                            al[mt][jj] = (short)(qa[jj] & 0xffffu);
                        }
                    } else {
                        float4 f0 = *(const float4*)(Alast_f32 + boff);
                        float4 f1 = *(const float4*)(Alast_f32 + boff + 4);
                        float fa[8] = {f0.x, f0.y, f0.z, f0.w, f1.x, f1.y, f1.z, f1.w};
                        #pragma unroll
                        for (int jj = 0; jj < 8; ++jj) {
                            short hh, ll;
                            splitf(fa[jj], hh, ll);
                            ah[mt][jj] = hh;
                            al[mt][jj] = ll;
                        }
                    }
                } else {
                    #pragma unroll
                    for (int jj = 0; jj < 8; ++jj) { ah[mt][jj] = 0; al[mt][jj] = 0; }
                }
            }
            #pragma unroll
            for (int nt = 0; nt < 8; ++nt) {
                short8v bh = *(const short8v*)&wlds[nt * 2048 + ks * 512 + lane * 8];
                short8v bl = *(const short8v*)&wlds[16384 + nt * 2048 + ks * 512 + lane * 8];
                #pragma unroll
                for (int mt = 0; mt < 4; ++mt)
                    acc[mt][nt] = __builtin_amdgcn_mfma_f32_16x16x32_bf16(ah[mt], bh, acc[mt][nt], 0, 0, 0);
                #pragma unroll
                for (int mt = 0; mt < 4; ++mt)
                    acc[mt][nt] = __builtin_amdgcn_mfma_f32_16x16x32_bf16(ah[mt], bl, acc[mt][nt], 0, 0, 0);
                #pragma unroll
                for (int mt = 0; mt < 4; ++mt)
                    acc[mt][nt] = __builtin_amdgcn_mfma_f32_16x16x32_bf16(al[mt], bh, acc[mt][nt], 0, 0, 0);
            }
        }
    }

    // epilogue: C/D layout col = lane&15, row = (lane>>4)*4 + reg  [m89]
    #pragma unroll
    for (int nt = 0; nt < 8; ++nt) {
        int col = nt * 16 + rl;
        float bv = bias[col];
        #pragma unroll
        for (int mt = 0; mt < 4; ++mt) {
            int r0 = rowTile + mt * 16 + ((lane >> 4) << 2);
            float4v c = acc[mt][nt];
            #pragma unroll
            for (int r = 0; r < 4; ++r) {
                int row = r0 + r;
                if (row >= M) continue;
                float v = c[r] + bv;
                if (mode == 0) {
                    v = fmaxf(v, 0.f);
                    outP[(size_t)row * D + col] = packsplit(v);
                } else if (mode == 1) {
                    outF[(size_t)row * D + col] = v;
                } else {
                    float* pp = outF + (size_t)row * D + col;
                    *pp = fmaxf(*pp, v);
                }
            }
        }
    }
}

// ------------------------------------------------------------------- driver
extern "C" void kernel_launch(void* const* d_in, const int* in_sizes, int n_in,
                              void* d_out, int out_size, void* d_ws, size_t ws_size,
                              hipStream_t stream) {
    const float* x_cui  = (const float*)d_in[0];
    const float* x_code = (const float*)d_in[1];
    const int*   ei_cc  = (const int*)d_in[2];
    const int*   ei_kc  = (const int*)d_in[3];
    const int*   ei_ck  = (const int*)d_in[4];
    const float* Wl     = (const float*)d_in[5];
    const float* Wr     = (const float*)d_in[6];
    const float* b      = (const float*)d_in[7];

    const int N_CUI  = in_sizes[0] / D;
    const int N_CODE = in_sizes[1] / D;
    const int E_CC   = in_sizes[2] / 2;
    const int E_KC   = in_sizes[3] / 2;
    const int E_CK   = in_sizes[4] / 2;
    const int NT = 2 * N_CUI + N_CODE;
    const int ET = E_CC + E_KC + E_CK;

    char* ws = (char*)d_ws;
    size_t off = 0;
    auto alloc = [&](size_t bytes) -> char* {
        char* p = ws + off;
        off += (bytes + 255) & ~(size_t)255;
        return p;
    };

    int*      cntAll    = (int*)alloc((size_t)NT * 4);      // must be first (memset)
    size_t cntBytes = (size_t)NT * 4;
    int*      offsAll   = (int*)alloc(((size_t)NT + 4) * 4);
    int*      curAll    = (int*)alloc((size_t)NT * 4);
    float*    invAll    = (float*)alloc((size_t)NT * 4);
    int*      blockSums = (int*)alloc(1024 * 4);
    int*      csrAll    = (int*)alloc((size_t)ET * 4);
    ushortT*  Wp        = (ushortT*)alloc((size_t)20 * 32768 * 2);
    float*    bcomb     = (float*)alloc(512 * 4);
    unsigned* aggP      = (unsigned*)alloc((size_t)NT * D * 4);
    unsigned* hcuiP0    = (unsigned*)alloc((size_t)N_CUI * D * 4);
    unsigned* hcuiP1    = (unsigned*)alloc((size_t)N_CUI * D * 4);
    unsigned* hcodeP0   = (unsigned*)alloc((size_t)N_CODE * D * 4);
    unsigned* hcodeP1   = (unsigned*)alloc((size_t)N_CODE * D * 4);

    float* out_cui  = (float*)d_out;
    float* out_code = (float*)d_out + (size_t)N_CUI * D;

    unsigned* hcP[2] = {hcuiP0, hcuiP1};
    unsigned* hkP[2] = {hcodeP0, hcodeP1};

    const unsigned* aggCC = aggP;
    const unsigned* aggKC = aggP + (size_t)N_CUI * D;
    const unsigned* aggCK = aggP + (size_t)2 * N_CUI * D;

    // ---- CSR build ----
    hipMemsetAsync(d_ws, 0, cntBytes, stream);
    count_all<<<2048, 256, 0, stream>>>(ei_cc, ei_kc, ei_ck, E_CC, E_KC, E_CK, N_CUI, cntAll);
    int n4 = NT >> 2;                       // NT divisible by 4 for these sizes
    int nb = (n4 + 1023) / 1024;
    scan_s1<<<nb, 1024, 0, stream>>>(cntAll, n4, blockSums);
    scan_s2<<<1, 1024, 0, stream>>>(blockSums, nb, offsAll, NT);
    scan_s3<<<nb, 1024, 0, stream>>>(cntAll, NT, blockSums, offsAll, curAll, invAll);
    place_all<<<2048, 256, 0, stream>>>(ei_cc, ei_kc, ei_ck, E_CC, E_KC, E_CK, N_CUI, curAll, csrAll);
    prep_w<<<161, 256, 0, stream>>>(Wl, Wr, b, Wp, bcomb);

    int aggGrid = (NT + 3) / 4;             // 4 waves / 256-thread block
    int gCui = (N_CUI + 255) / 256;
    int gCode = (N_CODE + 255) / 256;
    auto WpM = [&](int m) { return (const ushortT*)(Wp + (size_t)m * 32768); };

    // ---- layer 0: shared aggregation, then per-filter transforms (relu+pack) ----
    agg_all<<<aggGrid, 256, 0, stream>>>(x_cui, x_code, nullptr, nullptr, 0,
                                         csrAll, offsAll, invAll, N_CUI, N_CODE, aggP);
    for (int f = 0; f < 2; ++f) {
        int fl = f * 2;
        gemm_split<<<gCui, 256, 0, stream>>>(
            aggCC, aggKC, aggCC /*unused*/, x_cui,
            WpM(fl * 5 + 0), WpM(fl * 5 + 1), WpM(fl * 5 + 2),
            bcomb + fl * D, nullptr, hcP[f], N_CUI, 3, 0);
    }
    for (int f = 0; f < 2; ++f) {
        int fl = f * 2;
        gemm_split<<<gCode, 256, 0, stream>>>(
            aggCK, aggCK /*unused*/, aggCK /*unused*/, x_code,
            WpM(fl * 5 + 3), WpM(fl * 5 + 4), WpM(fl * 5 + 4),
            b + (size_t)(fl * 3 + 2) * D, nullptr, hkP[f], N_CODE, 2, 0);
    }

    // ---- layer 1: per-filter aggregation (packed gather) + final transforms ----
    for (int f = 0; f < 2; ++f) {
        int fl = f * 2 + 1;
        int mode = (f == 0) ? 1 : 2;
        agg_all<<<aggGrid, 256, 0, stream>>>(nullptr, nullptr, hcP[f], hkP[f], 1,
                                             csrAll, offsAll, invAll, N_CUI, N_CODE, aggP);
        gemm_split<<<gCui, 256, 0, stream>>>(
            aggCC, aggKC, hcP[f], nullptr,
            WpM(fl * 5 + 0), WpM(fl * 5 + 1), WpM(fl * 5 + 2),
            bcomb + fl * D, out_cui, nullptr, N_CUI, 3, mode);
        gemm_split<<<gCode, 256, 0, stream>>>(
            aggCK, hkP[f], hkP[f] /*unused*/, nullptr,
            WpM(fl * 5 + 3), WpM(fl * 5 + 4), WpM(fl * 5 + 4),
            b + (size_t)(fl * 3 + 2) * D, out_code, nullptr, N_CODE, 2, mode);
    }
}